// Round 4
// baseline (290.834 us; speedup 1.0000x reference)
//
#include <hip/hip_runtime.h>
#include <math.h>

#define D 64
#define K 4096
#define N 65536

typedef short s16x8 __attribute__((ext_vector_type(8)));
typedef short s16x4 __attribute__((ext_vector_type(4)));
typedef float f32x4 __attribute__((ext_vector_type(4)));

// round-to-nearest-even f32 -> bf16 (as raw short)
static __device__ inline short bf16_rne(float v) {
    unsigned u = __float_as_uint(v);
    unsigned r = (u + 0x7FFFu + ((u >> 16) & 1u)) >> 16;
    return (short)r;
}
static __device__ inline float bf16_f(short s) {
    return __uint_as_float(((unsigned)(unsigned short)s) << 16);
}

// ---------------- ws layout (in float units) ----------------
#define WS_COUNTS 0
#define WS_SUMS   (WS_COUNTS + K)
#define WS_SCAL   (WS_SUMS + K * D)          // 0=loss, 1=entropy, 2=n
#define WS_BIAS   (WS_SCAL + 8)              // -0.5*sum(e^2) per k
#define WS_ET     (WS_BIAS + K)              // e transposed [K][D] fp32
#define WS_ENC    (WS_ET + K * D)            // N ints
#define WS_LOSSP  (WS_ENC + N)               // 1024 loss partials
#define WS_XH     (WS_LOSSP + 1024)          // N*D bf16
#define WS_XL     (WS_XH + N * D / 2)
#define WS_EH     (WS_XL + N * D / 2)        // K*D bf16 fragment-ordered
#define WS_EL     (WS_EH + K * D / 2)
#define WS_ZERO_FLOATS (WS_SCAL + 8)

#define SCATTER_BLOCKS 1024
#define SCATTER_WAVES  (SCATTER_BLOCKS * 4)

#define AT 4                 // token-tiles (of 16) per wave = 64 tokens/wave
#define BT 8                 // code-tiles per LDS batch
#define NB (K / 16 / BT)     // 32 batches

// ---------------- prep: et [K][D], bias[k], eh/el B-fragment bf16 ----------
// eh[((t*2+c)*64 + l)*8 + j] = bf16(e[(c*32 + (l>>4)*8 + j)][t*16 + (l&15)])
__global__ __launch_bounds__(256) void k_prep_e(const float* __restrict__ e,
                                                short* __restrict__ eh,
                                                short* __restrict__ el,
                                                float* __restrict__ et,
                                                float* __restrict__ bias) {
    int gid = blockIdx.x * 256 + threadIdx.x;   // 32768 total: t*128 + c*64 + l
    int l = gid & 63;
    int c = (gid >> 6) & 1;
    int t = gid >> 7;
    int q = l >> 4;
    int n = l & 15;
    int d0 = c * 32 + q * 8;
    int k = t * 16 + n;

    __shared__ float sb[32];
    if (threadIdx.x < 32) sb[threadIdx.x] = 0.0f;
    __syncthreads();

    s16x8 h, lo;
    float vbuf[8];
    float ss = 0.0f;
#pragma unroll
    for (int j = 0; j < 8; ++j) {
        float v = e[(size_t)(d0 + j) * K + k];
        vbuf[j] = v;
        short hh = bf16_rne(v);
        h[j] = hh;
        lo[j] = bf16_rne(v - bf16_f(hh));
        ss = fmaf(v, v, ss);
    }
    ((s16x8*)eh)[gid] = h;
    ((s16x8*)el)[gid] = lo;
    // et rows: thread holds 8 consecutive d for fixed k -> two float4 stores
    float4* etp = (float4*)(et + (size_t)k * D + d0);
    etp[0] = make_float4(vbuf[0], vbuf[1], vbuf[2], vbuf[3]);
    etp[1] = make_float4(vbuf[4], vbuf[5], vbuf[6], vbuf[7]);

    atomicAdd(&sb[(t & 1) * 16 + n], ss);
    __syncthreads();
    if (c == 0 && q == 0) bias[k] = -0.5f * sb[(t & 1) * 16 + n];
}

// ---------------- prep: split x into bf16 hi/lo, [N][D] row-major ----------
__global__ __launch_bounds__(256) void k_split_x(const float* __restrict__ x,
                                                 short* __restrict__ xh,
                                                 short* __restrict__ xl) {
    int i = blockIdx.x * 256 + threadIdx.x;   // one float4 per thread
    const float4 v = ((const float4*)x)[i];
    s16x4 h, l;
    h.x = bf16_rne(v.x); l.x = bf16_rne(v.x - bf16_f(h.x));
    h.y = bf16_rne(v.y); l.y = bf16_rne(v.y - bf16_f(h.y));
    h.z = bf16_rne(v.z); l.z = bf16_rne(v.z - bf16_f(h.z));
    h.w = bf16_rne(v.w); l.w = bf16_rne(v.w - bf16_f(h.w));
    ((s16x4*)xh)[i] = h;
    ((s16x4*)xl)[i] = l;
}

// ---------------- main: MFMA argmin, 64 tokens per wave ----------------
// score = dot(x,e) - e2/2 (acc init = bias); argmax == argmin of distance.
// Block = 4 waves = 256 tokens; 1 block/CU. B fragments staged via LDS in
// 8-tile batches; one B read feeds 24 MFMAs (4 token-tiles x 6).
__global__ __launch_bounds__(256, 1) void k_argmin_mfma(const short* __restrict__ xh,
                                                        const short* __restrict__ xl,
                                                        const short* __restrict__ eh,
                                                        const short* __restrict__ el,
                                                        const float* __restrict__ bias,
                                                        int* __restrict__ enc) {
    const int tid = threadIdx.x;
    const int lane = tid & 63;
    const int wave = tid >> 6;
    const int quad = lane >> 4;
    const int n = lane & 15;
    const int tw0 = blockIdx.x * 256 + wave * 64;   // wave's first token

    // A fragments for 4 token-tiles x 2 D-chunks, hi and lo (64 VGPRs)
    s16x8 aH[AT][2], aL[AT][2];
#pragma unroll
    for (int tt = 0; tt < AT; ++tt)
#pragma unroll
        for (int c = 0; c < 2; ++c) {
            const size_t off = (size_t)(tw0 + tt * 16 + n) * D + c * 32 + quad * 8;
            aH[tt][c] = *(const s16x8*)(xh + off);
            aL[tt][c] = *(const s16x8*)(xl + off);
        }

    __shared__ short sEH[BT * 128 * 8];   // 16 KB
    __shared__ short sEL[BT * 128 * 8];   // 16 KB
    __shared__ float sB[BT * 16];

    const s16x8* ehv = (const s16x8*)eh;
    const s16x8* elv = (const s16x8*)el;
    const int sidx = tid & 127;
    const bool isH = tid < 128;
    const s16x8* src = isH ? ehv : elv;
    short* dst = isH ? sEH : sEL;

    // stage regs: batch 0
    s16x8 stg[BT];
#pragma unroll
    for (int u = 0; u < BT; ++u) stg[u] = src[u * 128 + sidx];
    float stgb = bias[sidx];

    float bestv[AT * 4];
    int besti[AT * 4];
#pragma unroll
    for (int i = 0; i < AT * 4; ++i) { bestv[i] = -3.4e38f; besti[i] = 0; }

    for (int tb = 0; tb < NB; ++tb) {
        __syncthreads();                       // prior batch's LDS reads done
#pragma unroll
        for (int u = 0; u < BT; ++u)
            *(s16x8*)&dst[(u * 128 + sidx) * 8] = stg[u];
        if (isH) sB[sidx] = stgb;
        __syncthreads();
        if (tb + 1 < NB) {                     // prefetch next batch
#pragma unroll
            for (int u = 0; u < BT; ++u)
                stg[u] = src[(tb + 1) * BT * 128 + u * 128 + sidx];
            stgb = bias[(tb + 1) * 128 + sidx];
        }

#pragma unroll
        for (int u = 0; u < BT; ++u) {
            const s16x8 bh0 = *(const s16x8*)&sEH[(u * 128 + lane) * 8];
            const s16x8 bh1 = *(const s16x8*)&sEH[(u * 128 + 64 + lane) * 8];
            const s16x8 bl0 = *(const s16x8*)&sEL[(u * 128 + lane) * 8];
            const s16x8 bl1 = *(const s16x8*)&sEL[(u * 128 + 64 + lane) * 8];
            const float bb = sB[u * 16 + n];
            const int kidx = tb * BT * 16 + u * 16 + n;
#pragma unroll
            for (int tt = 0; tt < AT; ++tt) {
                f32x4 acc = {bb, bb, bb, bb};
                acc = __builtin_amdgcn_mfma_f32_16x16x32_bf16(aH[tt][0], bh0, acc, 0, 0, 0);
                acc = __builtin_amdgcn_mfma_f32_16x16x32_bf16(aH[tt][1], bh1, acc, 0, 0, 0);
                acc = __builtin_amdgcn_mfma_f32_16x16x32_bf16(aH[tt][0], bl0, acc, 0, 0, 0);
                acc = __builtin_amdgcn_mfma_f32_16x16x32_bf16(aH[tt][1], bl1, acc, 0, 0, 0);
                acc = __builtin_amdgcn_mfma_f32_16x16x32_bf16(aL[tt][0], bh0, acc, 0, 0, 0);
                acc = __builtin_amdgcn_mfma_f32_16x16x32_bf16(aL[tt][1], bh1, acc, 0, 0, 0);
#pragma unroll
                for (int r = 0; r < 4; ++r) {
                    bool gt = acc[r] > bestv[tt * 4 + r];   // ascending k: first max kept
                    bestv[tt * 4 + r] = gt ? acc[r] : bestv[tt * 4 + r];
                    besti[tt * 4 + r] = gt ? kidx : besti[tt * 4 + r];
                }
            }
        }
    }

    // reduce across the 16-lane column group (xor 1,2,4,8 stays in group)
#pragma unroll
    for (int off = 1; off < 16; off <<= 1) {
#pragma unroll
        for (int i = 0; i < AT * 4; ++i) {
            float vv = __shfl_xor(bestv[i], off, 64);
            int ii = __shfl_xor(besti[i], off, 64);
            bool take = (vv > bestv[i]) || (vv == bestv[i] && ii < besti[i]);
            bestv[i] = take ? vv : bestv[i];
            besti[i] = take ? ii : besti[i];
        }
    }
    if (n == 0) {
#pragma unroll
        for (int tt = 0; tt < AT; ++tt)
#pragma unroll
            for (int r = 0; r < 4; ++r)
                enc[tw0 + tt * 16 + quad * 4 + r] = besti[tt * 4 + r];
    }
}

// ---------------- gather/scatter: quantized_st, loss partials, counts, sums --
// lane -> (token = lane>>4, d4 = lane&15): float4 per lane, 4 tokens/wave/iter.
__global__ __launch_bounds__(256) void k_scatter(const float* __restrict__ x,
                                                 const float* __restrict__ et,
                                                 const int* __restrict__ enc,
                                                 float* __restrict__ out_q,
                                                 float* __restrict__ counts,
                                                 float* __restrict__ sums,
                                                 float* __restrict__ lossp) {
    const int lane = threadIdx.x & 63;
    const int wave = threadIdx.x >> 6;
    const int wid = blockIdx.x * 4 + wave;
    const int tsub = lane >> 4;      // which of the 4 tokens
    const int d4 = lane & 15;        // float4 index within the row

    float lacc = 0.0f;
    for (int qi = wid; qi < N / 4; qi += SCATTER_WAVES) {
        const int tok = qi * 4 + tsub;
        const int idx = enc[tok];
        const float4 xv = ((const float4*)x)[(size_t)qi * 64 + lane];
        const float4 qv = ((const float4*)et)[(size_t)idx * 16 + d4];
        float4 o;
        float t;
        t = qv.x - xv.x; o.x = xv.x + t; lacc = fmaf(t, t, lacc);
        t = qv.y - xv.y; o.y = xv.y + t; lacc = fmaf(t, t, lacc);
        t = qv.z - xv.z; o.z = xv.z + t; lacc = fmaf(t, t, lacc);
        t = qv.w - xv.w; o.w = xv.w + t; lacc = fmaf(t, t, lacc);
        ((float4*)out_q)[(size_t)qi * 64 + lane] = o;

        float* srow = sums + (size_t)idx * D + d4 * 4;
        atomicAdd(srow + 0, xv.x);
        atomicAdd(srow + 1, xv.y);
        atomicAdd(srow + 2, xv.z);
        atomicAdd(srow + 3, xv.w);
        if (d4 == 0) atomicAdd(&counts[idx], 1.0f);
    }
#pragma unroll
    for (int off = 32; off > 0; off >>= 1) lacc += __shfl_xor(lacc, off, 64);
    __shared__ float sl[4];
    if (lane == 0) sl[wave] = lacc;
    __syncthreads();
    if (threadIdx.x == 0)
        lossp[blockIdx.x] = (sl[0] + sl[1]) + (sl[2] + sl[3]);
}

// ---------------- per-k stats + loss-partial reduce ----------------
__global__ __launch_bounds__(256) void k_stats(const float* __restrict__ counts,
                                               const float* __restrict__ cs,
                                               const float* __restrict__ lossp,
                                               float* __restrict__ out_ncs,
                                               float* __restrict__ scal) {
    const int k = blockIdx.x * 256 + threadIdx.x;
    const int lane = threadIdx.x & 63;
    const int wave = threadIdx.x >> 6;
    float c = counts[k];
    float ncs = 0.1f * c + 0.9f * cs[k];
    out_ncs[k] = ncs;
    float p = c * (1.0f / 65536.0f);
    float h = p * logf(p + 1e-20f);

    float a = ncs, b = h;
#pragma unroll
    for (int off = 32; off > 0; off >>= 1) {
        a += __shfl_xor(a, off, 64);
        b += __shfl_xor(b, off, 64);
    }
    __shared__ float sa[4], sb[4];
    if (lane == 0) { sa[wave] = a; sb[wave] = b; }
    __syncthreads();
    if (threadIdx.x == 0) {
        atomicAdd(&scal[2], (sa[0] + sa[1]) + (sa[2] + sa[3]));
        atomicAdd(&scal[1], (sb[0] + sb[1]) + (sb[2] + sb[3]));
    }

    if (blockIdx.x == 0) {
        float l = 0.0f;
#pragma unroll
        for (int j = 0; j < SCATTER_BLOCKS / 256; ++j)
            l += lossp[threadIdx.x + j * 256];
#pragma unroll
        for (int off = 32; off > 0; off >>= 1) l += __shfl_xor(l, off, 64);
        __shared__ float sc[4];
        if (lane == 0) sc[wave] = l;
        __syncthreads();
        if (threadIdx.x == 0)
            scal[0] = (sc[0] + sc[1]) + (sc[2] + sc[3]);
    }
}

// ---------------- finalize ----------------
__global__ __launch_bounds__(256) void k_final(const float* __restrict__ sums,
                                               const float* __restrict__ un,
                                               const float* __restrict__ ncs,
                                               const float* __restrict__ scal,
                                               float* __restrict__ out_ne,
                                               float* __restrict__ out_nun,
                                               float* __restrict__ out_loss,
                                               float* __restrict__ out_ppl) {
    const int i = blockIdx.x * 256 + threadIdx.x;  // i = d*K + k
    const int d = i >> 12;
    const int k = i & (K - 1);
    float nun = 0.1f * sums[k * D + d] + 0.9f * un[i];
    out_nun[i] = nun;
    float nn = scal[2];
    float stable = (ncs[k] + 1e-20f) / (nn + (float)K * 1e-20f) * nn;
    out_ne[i] = nun / stable;
    if (i == 0) {
        out_loss[0] = 0.25f * (scal[0] * (1.0f / 4194304.0f));
        out_ppl[0] = expf(-scal[1]);
    }
}

extern "C" void kernel_launch(void* const* d_in, const int* in_sizes, int n_in,
                              void* d_out, int out_size, void* d_ws, size_t ws_size,
                              hipStream_t stream) {
    const float* x  = (const float*)d_in[0];
    const float* e  = (const float*)d_in[1];
    const float* cs = (const float*)d_in[2];
    const float* un = (const float*)d_in[3];

    float* ws = (float*)d_ws;
    float* counts = ws + WS_COUNTS;
    float* sums   = ws + WS_SUMS;
    float* scal   = ws + WS_SCAL;
    float* bias   = ws + WS_BIAS;
    float* et     = ws + WS_ET;
    int*   enc    = (int*)(ws + WS_ENC);
    float* lossp  = ws + WS_LOSSP;
    short* xh     = (short*)(ws + WS_XH);
    short* xl     = (short*)(ws + WS_XL);
    short* eh     = (short*)(ws + WS_EH);
    short* el     = (short*)(ws + WS_EL);

    float* out      = (float*)d_out;
    float* out_q    = out;                          // [N,D]
    float* out_loss = out + (size_t)N * D;
    float* out_ppl  = out_loss + 1;
    float* out_ne   = out_ppl + 1;                  // [D,K]
    float* out_ncs  = out_ne + (size_t)D * K;       // [K]
    float* out_nun  = out_ncs + K;                  // [D,K]

    hipMemsetAsync(d_ws, 0, (size_t)WS_ZERO_FLOATS * sizeof(float), stream);
    k_prep_e<<<K / 16 * 128 / 256, 256, 0, stream>>>(e, eh, el, et, bias);
    k_split_x<<<N * D / 4 / 256, 256, 0, stream>>>(x, xh, xl);
    k_argmin_mfma<<<N / 256, 256, 0, stream>>>(xh, xl, eh, el, bias, enc);
    k_scatter<<<SCATTER_BLOCKS, 256, 0, stream>>>(x, et, enc, out_q, counts, sums, lossp);
    k_stats<<<K / 256, 256, 0, stream>>>(counts, cs, lossp, out_ncs, scal);
    k_final<<<D * K / 256, 256, 0, stream>>>(sums, un, out_ncs, scal,
                                             out_ne, out_nun, out_loss, out_ppl);
}

// Round 5
// 275.750 us; speedup vs baseline: 1.0547x; 1.0547x over previous
//
#include <hip/hip_runtime.h>
#include <math.h>

#define D 64
#define K 4096
#define N 65536

typedef short s16x8 __attribute__((ext_vector_type(8)));
typedef short s16x4 __attribute__((ext_vector_type(4)));
typedef float f32x4 __attribute__((ext_vector_type(4)));

// round-to-nearest-even f32 -> bf16 (as raw short)
static __device__ inline short bf16_rne(float v) {
    unsigned u = __float_as_uint(v);
    unsigned r = (u + 0x7FFFu + ((u >> 16) & 1u)) >> 16;
    return (short)r;
}
static __device__ inline float bf16_f(short s) {
    return __uint_as_float(((unsigned)(unsigned short)s) << 16);
}

// ---------------- ws layout (in float units) ----------------
#define WS_COUNTS 0                          // K floats (atomic histogram)
#define WS_SCAL   (WS_COUNTS + K)            // 8: 0=loss, 1=entropy, 2=n
#define WS_CURSOR (WS_SCAL + 8)              // K ints (perm cursors)
#define WS_START  (WS_CURSOR + K)            // K ints (segment starts)
#define WS_BIAS   (WS_START + K)             // K floats: -0.5*sum(e^2)
#define WS_ORDER  (WS_BIAS + K)              // N ints (tokens sorted by code)
#define WS_ENC    (WS_ORDER + N)             // N ints
#define WS_LOSSP  (WS_ENC + N)               // 1024 loss partials
#define WS_SUMS   (WS_LOSSP + 1024)          // K*D floats (plain stores)
#define WS_ET     (WS_SUMS + K * D)          // K*D floats: e transposed [K][D]
#define WS_XH     (WS_ET + K * D)            // N*D bf16
#define WS_XL     (WS_XH + N * D / 2)
#define WS_EH     (WS_XL + N * D / 2)        // K*D bf16 fragment-ordered
#define WS_EL     (WS_EH + K * D / 2)
#define WS_ZERO_FLOATS (WS_CURSOR + K)       // zero counts+scal+cursor

#define AT 4                 // token-tiles (of 16) per wave = 64 tokens/wave
#define BT 8                 // code-tiles per LDS batch
#define NB (K / 16 / BT)     // 32 batches

#define QBLOCKS 1024

// ---------------- prep: et [K][D], bias[k], eh/el B-fragment bf16 ----------
__global__ __launch_bounds__(256) void k_prep_e(const float* __restrict__ e,
                                                short* __restrict__ eh,
                                                short* __restrict__ el,
                                                float* __restrict__ et,
                                                float* __restrict__ bias) {
    int gid = blockIdx.x * 256 + threadIdx.x;   // 32768 total: t*128 + c*64 + l
    int l = gid & 63;
    int c = (gid >> 6) & 1;
    int t = gid >> 7;
    int q = l >> 4;
    int n = l & 15;
    int d0 = c * 32 + q * 8;
    int k = t * 16 + n;

    __shared__ float sb[32];
    if (threadIdx.x < 32) sb[threadIdx.x] = 0.0f;
    __syncthreads();

    s16x8 h, lo;
    float vbuf[8];
    float ss = 0.0f;
#pragma unroll
    for (int j = 0; j < 8; ++j) {
        float v = e[(size_t)(d0 + j) * K + k];
        vbuf[j] = v;
        short hh = bf16_rne(v);
        h[j] = hh;
        lo[j] = bf16_rne(v - bf16_f(hh));
        ss = fmaf(v, v, ss);
    }
    ((s16x8*)eh)[gid] = h;
    ((s16x8*)el)[gid] = lo;
    float4* etp = (float4*)(et + (size_t)k * D + d0);
    etp[0] = make_float4(vbuf[0], vbuf[1], vbuf[2], vbuf[3]);
    etp[1] = make_float4(vbuf[4], vbuf[5], vbuf[6], vbuf[7]);

    atomicAdd(&sb[(t & 1) * 16 + n], ss);
    __syncthreads();
    if (c == 0 && q == 0) bias[k] = -0.5f * sb[(t & 1) * 16 + n];
}

// ---------------- prep: split x into bf16 hi/lo, [N][D] row-major ----------
__global__ __launch_bounds__(256) void k_split_x(const float* __restrict__ x,
                                                 short* __restrict__ xh,
                                                 short* __restrict__ xl) {
    int i = blockIdx.x * 256 + threadIdx.x;   // one float4 per thread
    const float4 v = ((const float4*)x)[i];
    s16x4 h, l;
    h.x = bf16_rne(v.x); l.x = bf16_rne(v.x - bf16_f(h.x));
    h.y = bf16_rne(v.y); l.y = bf16_rne(v.y - bf16_f(h.y));
    h.z = bf16_rne(v.z); l.z = bf16_rne(v.z - bf16_f(h.z));
    h.w = bf16_rne(v.w); l.w = bf16_rne(v.w - bf16_f(h.w));
    ((s16x4*)xh)[i] = h;
    ((s16x4*)xl)[i] = l;
}

// ---------------- main: MFMA argmin, 64 tokens per wave ----------------
// score = dot(x,e) - e2/2 (acc init = bias); argmax == argmin of distance.
// Epilogue also builds the code histogram (counts).
__global__ __launch_bounds__(256, 1) void k_argmin_mfma(const short* __restrict__ xh,
                                                        const short* __restrict__ xl,
                                                        const short* __restrict__ eh,
                                                        const short* __restrict__ el,
                                                        const float* __restrict__ bias,
                                                        int* __restrict__ enc,
                                                        float* __restrict__ counts) {
    const int tid = threadIdx.x;
    const int lane = tid & 63;
    const int wave = tid >> 6;
    const int quad = lane >> 4;
    const int n = lane & 15;
    const int tw0 = blockIdx.x * 256 + wave * 64;   // wave's first token

    s16x8 aH[AT][2], aL[AT][2];
#pragma unroll
    for (int tt = 0; tt < AT; ++tt)
#pragma unroll
        for (int c = 0; c < 2; ++c) {
            const size_t off = (size_t)(tw0 + tt * 16 + n) * D + c * 32 + quad * 8;
            aH[tt][c] = *(const s16x8*)(xh + off);
            aL[tt][c] = *(const s16x8*)(xl + off);
        }

    __shared__ short sEH[BT * 128 * 8];   // 16 KB
    __shared__ short sEL[BT * 128 * 8];   // 16 KB
    __shared__ float sB[BT * 16];

    const s16x8* ehv = (const s16x8*)eh;
    const s16x8* elv = (const s16x8*)el;
    const int sidx = tid & 127;
    const bool isH = tid < 128;
    const s16x8* src = isH ? ehv : elv;
    short* dst = isH ? sEH : sEL;

    s16x8 stg[BT];
#pragma unroll
    for (int u = 0; u < BT; ++u) stg[u] = src[u * 128 + sidx];
    float stgb = bias[sidx];

    float bestv[AT * 4];
    int besti[AT * 4];
#pragma unroll
    for (int i = 0; i < AT * 4; ++i) { bestv[i] = -3.4e38f; besti[i] = 0; }

    for (int tb = 0; tb < NB; ++tb) {
        __syncthreads();
#pragma unroll
        for (int u = 0; u < BT; ++u)
            *(s16x8*)&dst[(u * 128 + sidx) * 8] = stg[u];
        if (isH) sB[sidx] = stgb;
        __syncthreads();
        if (tb + 1 < NB) {
#pragma unroll
            for (int u = 0; u < BT; ++u)
                stg[u] = src[(tb + 1) * BT * 128 + u * 128 + sidx];
            stgb = bias[(tb + 1) * 128 + sidx];
        }

#pragma unroll
        for (int u = 0; u < BT; ++u) {
            const s16x8 bh0 = *(const s16x8*)&sEH[(u * 128 + lane) * 8];
            const s16x8 bh1 = *(const s16x8*)&sEH[(u * 128 + 64 + lane) * 8];
            const s16x8 bl0 = *(const s16x8*)&sEL[(u * 128 + lane) * 8];
            const s16x8 bl1 = *(const s16x8*)&sEL[(u * 128 + 64 + lane) * 8];
            const float bb = sB[u * 16 + n];
            const int kidx = tb * BT * 16 + u * 16 + n;
#pragma unroll
            for (int tt = 0; tt < AT; ++tt) {
                f32x4 acc = {bb, bb, bb, bb};
                acc = __builtin_amdgcn_mfma_f32_16x16x32_bf16(aH[tt][0], bh0, acc, 0, 0, 0);
                acc = __builtin_amdgcn_mfma_f32_16x16x32_bf16(aH[tt][1], bh1, acc, 0, 0, 0);
                acc = __builtin_amdgcn_mfma_f32_16x16x32_bf16(aH[tt][0], bl0, acc, 0, 0, 0);
                acc = __builtin_amdgcn_mfma_f32_16x16x32_bf16(aH[tt][1], bl1, acc, 0, 0, 0);
                acc = __builtin_amdgcn_mfma_f32_16x16x32_bf16(aL[tt][0], bh0, acc, 0, 0, 0);
                acc = __builtin_amdgcn_mfma_f32_16x16x32_bf16(aL[tt][1], bh1, acc, 0, 0, 0);
#pragma unroll
                for (int r = 0; r < 4; ++r) {
                    bool gt = acc[r] > bestv[tt * 4 + r];   // ascending k: first max
                    bestv[tt * 4 + r] = gt ? acc[r] : bestv[tt * 4 + r];
                    besti[tt * 4 + r] = gt ? kidx : besti[tt * 4 + r];
                }
            }
        }
    }

#pragma unroll
    for (int off = 1; off < 16; off <<= 1) {
#pragma unroll
        for (int i = 0; i < AT * 4; ++i) {
            float vv = __shfl_xor(bestv[i], off, 64);
            int ii = __shfl_xor(besti[i], off, 64);
            bool take = (vv > bestv[i]) || (vv == bestv[i] && ii < besti[i]);
            bestv[i] = take ? vv : bestv[i];
            besti[i] = take ? ii : besti[i];
        }
    }
    if (n == 0) {
#pragma unroll
        for (int tt = 0; tt < AT; ++tt)
#pragma unroll
            for (int r = 0; r < 4; ++r) {
                int bi = besti[tt * 4 + r];
                enc[tw0 + tt * 16 + quad * 4 + r] = bi;
                atomicAdd(&counts[bi], 1.0f);   // histogram
            }
    }
}

// ---------------- exclusive scan of counts -> start[] (single block) -------
__global__ __launch_bounds__(256) void k_scan(const float* __restrict__ counts,
                                              int* __restrict__ start) {
    const int t = threadIdx.x;
    int local[16];
    int s = 0;
#pragma unroll
    for (int j = 0; j < 16; ++j) {
        local[j] = s;
        s += (int)counts[t * 16 + j];
    }
    __shared__ int ts[256];
    ts[t] = s;
    __syncthreads();
    if (t == 0) {
        int a = 0;
        for (int i = 0; i < 256; ++i) { int v = ts[i]; ts[i] = a; a += v; }
    }
    __syncthreads();
    const int off = ts[t];
#pragma unroll
    for (int j = 0; j < 16; ++j) start[t * 16 + j] = off + local[j];
}

// ---------------- build permutation: tokens grouped by code ----------------
__global__ __launch_bounds__(256) void k_perm(const int* __restrict__ enc,
                                              const int* __restrict__ start,
                                              int* __restrict__ cursor,
                                              int* __restrict__ order) {
    const int tok = blockIdx.x * 256 + threadIdx.x;
    const int idx = enc[tok];
    const int slot = start[idx] + atomicAdd(&cursor[idx], 1);
    order[slot] = tok;
}

// ---------------- segmented sums: one wave per code, NO atomics ------------
__global__ __launch_bounds__(256) void k_sums(const float* __restrict__ x,
                                              const int* __restrict__ order,
                                              const int* __restrict__ start,
                                              const float* __restrict__ counts,
                                              float* __restrict__ sums) {
    const int lane = threadIdx.x & 63;
    const int w = blockIdx.x * 4 + (threadIdx.x >> 6);   // code id
    const int s0 = start[w];
    const int cnt = (int)counts[w];

    float a = 0.0f, b = 0.0f;
    int j = 0;
    for (; j + 1 < cnt; j += 2) {
        const int t0 = order[s0 + j];
        const int t1 = order[s0 + j + 1];
        a += x[(size_t)t0 * D + lane];
        b += x[(size_t)t1 * D + lane];
    }
    if (j < cnt) a += x[(size_t)order[s0 + j] * D + lane];
    sums[(size_t)w * D + lane] = a + b;
}

// ---------------- streaming quantize: out_q + loss partials, NO atomics ----
__global__ __launch_bounds__(256) void k_quant(const float* __restrict__ x,
                                               const float* __restrict__ et,
                                               const int* __restrict__ enc,
                                               float* __restrict__ out_q,
                                               float* __restrict__ lossp) {
    const int lane = threadIdx.x & 63;
    const int wave = threadIdx.x >> 6;
    float lacc = 0.0f;
#pragma unroll
    for (int it = 0; it < 4; ++it) {
        const int i = (blockIdx.x * 256 + threadIdx.x) + it * (QBLOCKS * 256);
        const int token = i >> 4;
        const int d4 = i & 15;
        const int idx = enc[token];
        const float4 xv = ((const float4*)x)[i];
        const float4 qv = ((const float4*)et)[(size_t)idx * 16 + d4];
        float4 o;
        float t;
        t = qv.x - xv.x; o.x = xv.x + t; lacc = fmaf(t, t, lacc);
        t = qv.y - xv.y; o.y = xv.y + t; lacc = fmaf(t, t, lacc);
        t = qv.z - xv.z; o.z = xv.z + t; lacc = fmaf(t, t, lacc);
        t = qv.w - xv.w; o.w = xv.w + t; lacc = fmaf(t, t, lacc);
        ((float4*)out_q)[i] = o;
    }
#pragma unroll
    for (int off = 32; off > 0; off >>= 1) lacc += __shfl_xor(lacc, off, 64);
    __shared__ float sl[4];
    if (lane == 0) sl[wave] = lacc;
    __syncthreads();
    if (threadIdx.x == 0)
        lossp[blockIdx.x] = (sl[0] + sl[1]) + (sl[2] + sl[3]);
}

// ---------------- per-k stats + loss-partial reduce ----------------
__global__ __launch_bounds__(256) void k_stats(const float* __restrict__ counts,
                                               const float* __restrict__ cs,
                                               const float* __restrict__ lossp,
                                               float* __restrict__ out_ncs,
                                               float* __restrict__ scal) {
    const int k = blockIdx.x * 256 + threadIdx.x;
    const int lane = threadIdx.x & 63;
    const int wave = threadIdx.x >> 6;
    float c = counts[k];
    float ncs = 0.1f * c + 0.9f * cs[k];
    out_ncs[k] = ncs;
    float p = c * (1.0f / 65536.0f);
    float h = p * logf(p + 1e-20f);

    float a = ncs, b = h;
#pragma unroll
    for (int off = 32; off > 0; off >>= 1) {
        a += __shfl_xor(a, off, 64);
        b += __shfl_xor(b, off, 64);
    }
    __shared__ float sa[4], sb[4];
    if (lane == 0) { sa[wave] = a; sb[wave] = b; }
    __syncthreads();
    if (threadIdx.x == 0) {
        atomicAdd(&scal[2], (sa[0] + sa[1]) + (sa[2] + sa[3]));
        atomicAdd(&scal[1], (sb[0] + sb[1]) + (sb[2] + sb[3]));
    }

    if (blockIdx.x == 0) {
        float l = 0.0f;
#pragma unroll
        for (int j = 0; j < QBLOCKS / 256; ++j)
            l += lossp[threadIdx.x + j * 256];
#pragma unroll
        for (int off = 32; off > 0; off >>= 1) l += __shfl_xor(l, off, 64);
        __shared__ float sc[4];
        if (lane == 0) sc[wave] = l;
        __syncthreads();
        if (threadIdx.x == 0)
            scal[0] = (sc[0] + sc[1]) + (sc[2] + sc[3]);
    }
}

// ---------------- finalize ----------------
__global__ __launch_bounds__(256) void k_final(const float* __restrict__ sums,
                                               const float* __restrict__ un,
                                               const float* __restrict__ ncs,
                                               const float* __restrict__ scal,
                                               float* __restrict__ out_ne,
                                               float* __restrict__ out_nun,
                                               float* __restrict__ out_loss,
                                               float* __restrict__ out_ppl) {
    const int i = blockIdx.x * 256 + threadIdx.x;  // i = d*K + k
    const int d = i >> 12;
    const int k = i & (K - 1);
    float nun = 0.1f * sums[k * D + d] + 0.9f * un[i];
    out_nun[i] = nun;
    float nn = scal[2];
    float stable = (ncs[k] + 1e-20f) / (nn + (float)K * 1e-20f) * nn;
    out_ne[i] = nun / stable;
    if (i == 0) {
        out_loss[0] = 0.25f * (scal[0] * (1.0f / 4194304.0f));
        out_ppl[0] = expf(-scal[1]);
    }
}

extern "C" void kernel_launch(void* const* d_in, const int* in_sizes, int n_in,
                              void* d_out, int out_size, void* d_ws, size_t ws_size,
                              hipStream_t stream) {
    const float* x  = (const float*)d_in[0];
    const float* e  = (const float*)d_in[1];
    const float* cs = (const float*)d_in[2];
    const float* un = (const float*)d_in[3];

    float* ws = (float*)d_ws;
    float* counts = ws + WS_COUNTS;
    float* scal   = ws + WS_SCAL;
    int*   cursor = (int*)(ws + WS_CURSOR);
    int*   startp = (int*)(ws + WS_START);
    float* bias   = ws + WS_BIAS;
    int*   order  = (int*)(ws + WS_ORDER);
    int*   enc    = (int*)(ws + WS_ENC);
    float* lossp  = ws + WS_LOSSP;
    float* sums   = ws + WS_SUMS;
    float* et     = ws + WS_ET;
    short* xh     = (short*)(ws + WS_XH);
    short* xl     = (short*)(ws + WS_XL);
    short* eh     = (short*)(ws + WS_EH);
    short* el     = (short*)(ws + WS_EL);

    float* out      = (float*)d_out;
    float* out_q    = out;                          // [N,D]
    float* out_loss = out + (size_t)N * D;
    float* out_ppl  = out_loss + 1;
    float* out_ne   = out_ppl + 1;                  // [D,K]
    float* out_ncs  = out_ne + (size_t)D * K;       // [K]
    float* out_nun  = out_ncs + K;                  // [D,K]

    hipMemsetAsync(d_ws, 0, (size_t)WS_ZERO_FLOATS * sizeof(float), stream);
    k_prep_e<<<K / 16 * 128 / 256, 256, 0, stream>>>(e, eh, el, et, bias);
    k_split_x<<<N * D / 4 / 256, 256, 0, stream>>>(x, xh, xl);
    k_argmin_mfma<<<N / 256, 256, 0, stream>>>(xh, xl, eh, el, bias, enc, counts);
    k_scan<<<1, 256, 0, stream>>>(counts, startp);
    k_perm<<<N / 256, 256, 0, stream>>>(enc, startp, cursor, order);
    k_sums<<<K / 4, 256, 0, stream>>>(x, order, startp, counts, sums);
    k_quant<<<QBLOCKS, 256, 0, stream>>>(x, et, enc, out_q, lossp);
    k_stats<<<K / 256, 256, 0, stream>>>(counts, cs, lossp, out_ncs, scal);
    k_final<<<D * K / 256, 256, 0, stream>>>(sums, un, out_ncs, scal,
                                             out_ne, out_nun, out_loss, out_ppl);
}

// Round 6
// 270.086 us; speedup vs baseline: 1.0768x; 1.0210x over previous
//
#include <hip/hip_runtime.h>
#include <math.h>

#define D 64
#define K 4096
#define N 65536

typedef short s16x8 __attribute__((ext_vector_type(8)));
typedef short s16x4 __attribute__((ext_vector_type(4)));
typedef float f32x4 __attribute__((ext_vector_type(4)));

// round-to-nearest-even f32 -> bf16 (as raw short)
static __device__ inline short bf16_rne(float v) {
    unsigned u = __float_as_uint(v);
    unsigned r = (u + 0x7FFFu + ((u >> 16) & 1u)) >> 16;
    return (short)r;
}
static __device__ inline float bf16_f(short s) {
    return __uint_as_float(((unsigned)(unsigned short)s) << 16);
}

// ---------------- ws layout (in float units) ----------------
#define WS_COUNTS 0                          // K floats (atomic histogram)
#define WS_SCAL   (WS_COUNTS + K)            // 8: 0=sum(dist), 1=entropy, 2=n
#define WS_CURSOR (WS_SCAL + 8)              // K ints (perm cursors)
#define WS_START  (WS_CURSOR + K)            // K ints (segment starts)
#define WS_BIAS   (WS_START + K)             // K floats: -0.5*sum(e^2)
#define WS_ORDER  (WS_BIAS + K)              // N ints (tokens grouped by code)
#define WS_ENC    (WS_ORDER + N)             // N ints
#define WS_LOSSP  (WS_ENC + N)               // 512 loss partials (alloc 1024)
#define WS_X2     (WS_LOSSP + 1024)          // N floats: ||x_row||^2
#define WS_SUMS   (WS_X2 + N)                // K*D floats (plain stores)
#define WS_ET     (WS_SUMS + K * D)          // K*D floats: e transposed [K][D]
#define WS_XH     (WS_ET + K * D)            // N*D bf16
#define WS_XL     (WS_XH + N * D / 2)
#define WS_EH     (WS_XL + N * D / 2)        // K*D bf16 fragment-ordered
#define WS_EL     (WS_EH + K * D / 2)
#define WS_ZERO_FLOATS (WS_CURSOR + K)       // zero counts+scal+cursor

#define AT 2                 // token-tiles (of 16) per wave = 32 tokens/wave
#define BT 8                 // code-tiles per LDS batch
#define NB (K / 16 / BT)     // 32 batches
#define ARGMIN_BLOCKS (N / (AT * 16 * 4))    // 512

#define QBLOCKS 1024

// ---------------- prep: et [K][D], bias[k], eh/el B-fragment bf16 ----------
__global__ __launch_bounds__(256) void k_prep_e(const float* __restrict__ e,
                                                short* __restrict__ eh,
                                                short* __restrict__ el,
                                                float* __restrict__ et,
                                                float* __restrict__ bias) {
    int gid = blockIdx.x * 256 + threadIdx.x;   // 32768 total: t*128 + c*64 + l
    int l = gid & 63;
    int c = (gid >> 6) & 1;
    int t = gid >> 7;
    int q = l >> 4;
    int n = l & 15;
    int d0 = c * 32 + q * 8;
    int k = t * 16 + n;

    __shared__ float sb[32];
    if (threadIdx.x < 32) sb[threadIdx.x] = 0.0f;
    __syncthreads();

    s16x8 h, lo;
    float vbuf[8];
    float ss = 0.0f;
#pragma unroll
    for (int j = 0; j < 8; ++j) {
        float v = e[(size_t)(d0 + j) * K + k];
        vbuf[j] = v;
        short hh = bf16_rne(v);
        h[j] = hh;
        lo[j] = bf16_rne(v - bf16_f(hh));
        ss = fmaf(v, v, ss);
    }
    ((s16x8*)eh)[gid] = h;
    ((s16x8*)el)[gid] = lo;
    float4* etp = (float4*)(et + (size_t)k * D + d0);
    etp[0] = make_float4(vbuf[0], vbuf[1], vbuf[2], vbuf[3]);
    etp[1] = make_float4(vbuf[4], vbuf[5], vbuf[6], vbuf[7]);

    atomicAdd(&sb[(t & 1) * 16 + n], ss);
    __syncthreads();
    if (c == 0 && q == 0) bias[k] = -0.5f * sb[(t & 1) * 16 + n];
}

// ---------------- prep: split x into bf16 hi/lo + per-token ||x||^2 --------
__global__ __launch_bounds__(256) void k_split_x(const float* __restrict__ x,
                                                 short* __restrict__ xh,
                                                 short* __restrict__ xl,
                                                 float* __restrict__ x2) {
    int i = blockIdx.x * 256 + threadIdx.x;   // one float4 per thread
    const float4 v = ((const float4*)x)[i];
    s16x4 h, l;
    h.x = bf16_rne(v.x); l.x = bf16_rne(v.x - bf16_f(h.x));
    h.y = bf16_rne(v.y); l.y = bf16_rne(v.y - bf16_f(h.y));
    h.z = bf16_rne(v.z); l.z = bf16_rne(v.z - bf16_f(h.z));
    h.w = bf16_rne(v.w); l.w = bf16_rne(v.w - bf16_f(h.w));
    ((s16x4*)xh)[i] = h;
    ((s16x4*)xl)[i] = l;

    // ||x||^2: reduce the 16 lanes that share a token (aligned 16-groups)
    float sq = fmaf(v.x, v.x, fmaf(v.y, v.y, fmaf(v.z, v.z, v.w * v.w)));
    sq += __shfl_xor(sq, 1, 64);
    sq += __shfl_xor(sq, 2, 64);
    sq += __shfl_xor(sq, 4, 64);
    sq += __shfl_xor(sq, 8, 64);
    if ((threadIdx.x & 15) == 0) x2[i >> 4] = sq;
}

// ---------------- main: MFMA argmin, 32 tokens per wave ----------------
// score = dot(x,e) - e2/2 (acc init = bias); argmax == argmin of distance.
// Epilogue: enc, counts histogram, and per-block loss partial
// (dist = x2 - 2*score). 512 blocks -> 2 blocks/CU so MFMA/VALU overlap.
__global__ __launch_bounds__(256, 2) void k_argmin_mfma(const short* __restrict__ xh,
                                                        const short* __restrict__ xl,
                                                        const short* __restrict__ eh,
                                                        const short* __restrict__ el,
                                                        const float* __restrict__ bias,
                                                        const float* __restrict__ x2,
                                                        int* __restrict__ enc,
                                                        float* __restrict__ counts,
                                                        float* __restrict__ lossp) {
    const int tid = threadIdx.x;
    const int lane = tid & 63;
    const int wave = tid >> 6;
    const int quad = lane >> 4;
    const int n = lane & 15;
    const int tw0 = blockIdx.x * (AT * 16 * 4) + wave * (AT * 16);

    s16x8 aH[AT][2], aL[AT][2];
#pragma unroll
    for (int tt = 0; tt < AT; ++tt)
#pragma unroll
        for (int c = 0; c < 2; ++c) {
            const size_t off = (size_t)(tw0 + tt * 16 + n) * D + c * 32 + quad * 8;
            aH[tt][c] = *(const s16x8*)(xh + off);
            aL[tt][c] = *(const s16x8*)(xl + off);
        }

    __shared__ short sEH[BT * 128 * 8];   // 16 KB
    __shared__ short sEL[BT * 128 * 8];   // 16 KB
    __shared__ float sB[BT * 16];

    const s16x8* ehv = (const s16x8*)eh;
    const s16x8* elv = (const s16x8*)el;
    const int sidx = tid & 127;
    const bool isH = tid < 128;
    const s16x8* src = isH ? ehv : elv;
    short* dst = isH ? sEH : sEL;

    s16x8 stg[BT];
#pragma unroll
    for (int u = 0; u < BT; ++u) stg[u] = src[u * 128 + sidx];
    float stgb = bias[sidx];

    float bestv[AT * 4];
    int besti[AT * 4];
#pragma unroll
    for (int i = 0; i < AT * 4; ++i) { bestv[i] = -3.4e38f; besti[i] = 0; }

    for (int tb = 0; tb < NB; ++tb) {
        __syncthreads();
#pragma unroll
        for (int u = 0; u < BT; ++u)
            *(s16x8*)&dst[(u * 128 + sidx) * 8] = stg[u];
        if (isH) sB[sidx] = stgb;
        __syncthreads();
        if (tb + 1 < NB) {
#pragma unroll
            for (int u = 0; u < BT; ++u)
                stg[u] = src[(tb + 1) * BT * 128 + u * 128 + sidx];
            stgb = bias[(tb + 1) * 128 + sidx];
        }

#pragma unroll
        for (int u = 0; u < BT; ++u) {
            const s16x8 bh0 = *(const s16x8*)&sEH[(u * 128 + lane) * 8];
            const s16x8 bh1 = *(const s16x8*)&sEH[(u * 128 + 64 + lane) * 8];
            const s16x8 bl0 = *(const s16x8*)&sEL[(u * 128 + lane) * 8];
            const s16x8 bl1 = *(const s16x8*)&sEL[(u * 128 + 64 + lane) * 8];
            const float bb = sB[u * 16 + n];
            const int kidx = tb * BT * 16 + u * 16 + n;
#pragma unroll
            for (int tt = 0; tt < AT; ++tt) {
                f32x4 acc = {bb, bb, bb, bb};
                acc = __builtin_amdgcn_mfma_f32_16x16x32_bf16(aH[tt][0], bh0, acc, 0, 0, 0);
                acc = __builtin_amdgcn_mfma_f32_16x16x32_bf16(aH[tt][1], bh1, acc, 0, 0, 0);
                acc = __builtin_amdgcn_mfma_f32_16x16x32_bf16(aH[tt][0], bl0, acc, 0, 0, 0);
                acc = __builtin_amdgcn_mfma_f32_16x16x32_bf16(aH[tt][1], bl1, acc, 0, 0, 0);
                acc = __builtin_amdgcn_mfma_f32_16x16x32_bf16(aL[tt][0], bh0, acc, 0, 0, 0);
                acc = __builtin_amdgcn_mfma_f32_16x16x32_bf16(aL[tt][1], bh1, acc, 0, 0, 0);
#pragma unroll
                for (int r = 0; r < 4; ++r) {
                    bool gt = acc[r] > bestv[tt * 4 + r];   // ascending k: first max
                    bestv[tt * 4 + r] = gt ? acc[r] : bestv[tt * 4 + r];
                    besti[tt * 4 + r] = gt ? kidx : besti[tt * 4 + r];
                }
            }
        }
    }

#pragma unroll
    for (int off = 1; off < 16; off <<= 1) {
#pragma unroll
        for (int i = 0; i < AT * 4; ++i) {
            float vv = __shfl_xor(bestv[i], off, 64);
            int ii = __shfl_xor(besti[i], off, 64);
            bool take = (vv > bestv[i]) || (vv == bestv[i] && ii < besti[i]);
            bestv[i] = take ? vv : bestv[i];
            besti[i] = take ? ii : besti[i];
        }
    }
    float lsum = 0.0f;
    if (n == 0) {
#pragma unroll
        for (int tt = 0; tt < AT; ++tt)
#pragma unroll
            for (int r = 0; r < 4; ++r) {
                const int tok = tw0 + tt * 16 + quad * 4 + r;
                const int bi = besti[tt * 4 + r];
                enc[tok] = bi;
                atomicAdd(&counts[bi], 1.0f);   // histogram
                lsum += x2[tok] - 2.0f * bestv[tt * 4 + r];   // = min dist
            }
    }
#pragma unroll
    for (int off = 32; off > 0; off >>= 1) lsum += __shfl_xor(lsum, off, 64);
    __shared__ float sl[4];
    if (lane == 0) sl[wave] = lsum;
    __syncthreads();
    if (tid == 0) lossp[blockIdx.x] = (sl[0] + sl[1]) + (sl[2] + sl[3]);
}

// ---------------- single block: scan counts -> start; loss/entropy/n -------
__global__ __launch_bounds__(256) void k_scan(const float* __restrict__ counts,
                                              const float* __restrict__ cs,
                                              const float* __restrict__ lossp,
                                              int* __restrict__ start,
                                              float* __restrict__ scal) {
    const int t = threadIdx.x;
    const int lane = t & 63;
    const int wave = t >> 6;
    int local[16];
    int s = 0;
    float ent = 0.0f, scs = 0.0f;
#pragma unroll
    for (int j = 0; j < 16; ++j) {
        const int k = t * 16 + j;
        const float c = counts[k];
        local[j] = s;
        s += (int)c;
        const float p = c * (1.0f / 65536.0f);
        ent = fmaf(p, logf(p + 1e-20f), ent);
        scs += cs[k];
    }
    float lp = lossp[t] + lossp[t + 256];   // 512 partials

    __shared__ int ts[256];
    ts[t] = s;
    // reduce ent / scs / lp
    float a = ent, b = scs, c2 = lp;
#pragma unroll
    for (int off = 32; off > 0; off >>= 1) {
        a += __shfl_xor(a, off, 64);
        b += __shfl_xor(b, off, 64);
        c2 += __shfl_xor(c2, off, 64);
    }
    __shared__ float sa[4], sb[4], sc[4];
    if (lane == 0) { sa[wave] = a; sb[wave] = b; sc[wave] = c2; }
    __syncthreads();
    if (t == 0) {
        int acc = 0;
        for (int i = 0; i < 256; ++i) { int v = ts[i]; ts[i] = acc; acc += v; }
        scal[0] = (sc[0] + sc[1]) + (sc[2] + sc[3]);                 // sum dist
        scal[1] = (sa[0] + sa[1]) + (sa[2] + sa[3]);                 // entropy
        scal[2] = fmaf(0.9f, (sb[0] + sb[1]) + (sb[2] + sb[3]), 6553.6f); // n
    }
    __syncthreads();
    const int off = ts[t];
#pragma unroll
    for (int j = 0; j < 16; ++j) start[t * 16 + j] = off + local[j];
}

// ---------------- build permutation: tokens grouped by code ----------------
__global__ __launch_bounds__(256) void k_perm(const int* __restrict__ enc,
                                              const int* __restrict__ start,
                                              int* __restrict__ cursor,
                                              int* __restrict__ order) {
    const int tok = blockIdx.x * 256 + threadIdx.x;
    const int idx = enc[tok];
    const int slot = start[idx] + atomicAdd(&cursor[idx], 1);
    order[slot] = tok;
}

// ---------------- segmented sums: one wave per code, NO atomics ------------
__global__ __launch_bounds__(256) void k_sums(const float* __restrict__ x,
                                              const int* __restrict__ order,
                                              const int* __restrict__ start,
                                              const float* __restrict__ counts,
                                              float* __restrict__ sums) {
    const int lane = threadIdx.x & 63;
    const int w = blockIdx.x * 4 + (threadIdx.x >> 6);   // code id
    const int s0 = start[w];
    const int cnt = (int)counts[w];

    float a = 0.0f, b = 0.0f;
    int j = 0;
    for (; j + 1 < cnt; j += 2) {
        const int t0 = order[s0 + j];
        const int t1 = order[s0 + j + 1];
        a += x[(size_t)t0 * D + lane];
        b += x[(size_t)t1 * D + lane];
    }
    if (j < cnt) a += x[(size_t)order[s0 + j] * D + lane];
    sums[(size_t)w * D + lane] = a + b;
}

// ---------------- streaming quantize: out_q = et[enc] (pure gather) --------
__global__ __launch_bounds__(256) void k_quant(const float* __restrict__ et,
                                               const int* __restrict__ enc,
                                               float* __restrict__ out_q) {
#pragma unroll
    for (int it = 0; it < 4; ++it) {
        const int i = (blockIdx.x * 256 + threadIdx.x) + it * (QBLOCKS * 256);
        const int token = i >> 4;
        const int d4 = i & 15;
        const int idx = enc[token];
        ((float4*)out_q)[i] = ((const float4*)et)[(size_t)idx * 16 + d4];
    }
}

// ---------------- finalize: new_cs, new_un, new_e, loss, perplexity --------
__global__ __launch_bounds__(256) void k_final(const float* __restrict__ sums,
                                               const float* __restrict__ un,
                                               const float* __restrict__ counts,
                                               const float* __restrict__ cs,
                                               const float* __restrict__ scal,
                                               float* __restrict__ out_ne,
                                               float* __restrict__ out_ncs,
                                               float* __restrict__ out_nun,
                                               float* __restrict__ out_loss,
                                               float* __restrict__ out_ppl) {
    const int i = blockIdx.x * 256 + threadIdx.x;  // i = d*K + k
    const int d = i >> 12;
    const int k = i & (K - 1);
    const float ncs = 0.1f * counts[k] + 0.9f * cs[k];
    const float nun = 0.1f * sums[k * D + d] + 0.9f * un[i];
    out_nun[i] = nun;
    const float nn = scal[2];
    const float stable = (ncs + 1e-20f) / (nn + (float)K * 1e-20f) * nn;
    out_ne[i] = nun / stable;
    if (d == 0) out_ncs[k] = ncs;
    if (i == 0) {
        out_loss[0] = 0.25f * (scal[0] * (1.0f / 65536.0f));
        out_ppl[0] = expf(-scal[1]);
    }
}

extern "C" void kernel_launch(void* const* d_in, const int* in_sizes, int n_in,
                              void* d_out, int out_size, void* d_ws, size_t ws_size,
                              hipStream_t stream) {
    const float* x  = (const float*)d_in[0];
    const float* e  = (const float*)d_in[1];
    const float* cs = (const float*)d_in[2];
    const float* un = (const float*)d_in[3];

    float* ws = (float*)d_ws;
    float* counts = ws + WS_COUNTS;
    float* scal   = ws + WS_SCAL;
    int*   cursor = (int*)(ws + WS_CURSOR);
    int*   startp = (int*)(ws + WS_START);
    float* bias   = ws + WS_BIAS;
    int*   order  = (int*)(ws + WS_ORDER);
    int*   enc    = (int*)(ws + WS_ENC);
    float* lossp  = ws + WS_LOSSP;
    float* x2     = ws + WS_X2;
    float* sums   = ws + WS_SUMS;
    float* et     = ws + WS_ET;
    short* xh     = (short*)(ws + WS_XH);
    short* xl     = (short*)(ws + WS_XL);
    short* eh     = (short*)(ws + WS_EH);
    short* el     = (short*)(ws + WS_EL);

    float* out      = (float*)d_out;
    float* out_q    = out;                          // [N,D]
    float* out_loss = out + (size_t)N * D;
    float* out_ppl  = out_loss + 1;
    float* out_ne   = out_ppl + 1;                  // [D,K]
    float* out_ncs  = out_ne + (size_t)D * K;       // [K]
    float* out_nun  = out_ncs + K;                  // [D,K]

    hipMemsetAsync(d_ws, 0, (size_t)WS_ZERO_FLOATS * sizeof(float), stream);
    k_prep_e<<<K / 16 * 128 / 256, 256, 0, stream>>>(e, eh, el, et, bias);
    k_split_x<<<N * D / 4 / 256, 256, 0, stream>>>(x, xh, xl, x2);
    k_argmin_mfma<<<ARGMIN_BLOCKS, 256, 0, stream>>>(xh, xl, eh, el, bias, x2,
                                                     enc, counts, lossp);
    k_scan<<<1, 256, 0, stream>>>(counts, cs, lossp, startp, scal);
    k_perm<<<N / 256, 256, 0, stream>>>(enc, startp, cursor, order);
    k_sums<<<K / 4, 256, 0, stream>>>(x, order, startp, counts, sums);
    k_quant<<<QBLOCKS, 256, 0, stream>>>(et, enc, out_q);
    k_final<<<D * K / 256, 256, 0, stream>>>(sums, un, counts, cs, scal,
                                             out_ne, out_ncs, out_nun,
                                             out_loss, out_ppl);
}